// Round 1
// baseline (255.036 us; speedup 1.0000x reference)
//
#include <hip/hip_runtime.h>
#include <hip/hip_bf16.h>

// Problem: CSM_62216896250023
//   X:    (16384, 7)  int32 indices into vocab
//   emb:  (32000, 1024) f32
//   conv1,conv2: (2,1024) f32 ; conv3,conv4: (3,1024) f32
//   out = sigmoid(conv4(sigmoid(conv3(sigmoid(conv2(sigmoid(conv1(emb[X]))))))))
//   seq collapses 7 -> 6 -> 5 -> 3 -> 1 ; out (16384, 1024) f32
//
// Design: one block per batch row (256 threads), one float4 of E per thread.
// Each gathered emb-row load is exactly 256 lanes x 16B = the full 4KB row,
// perfectly coalesced. Per-channel conv weights (40KB total) stay hot in L1/L2.
// Sigmoid via native v_exp_f32 + v_rcp_f32.

constexpr int EMBED = 1024;
constexpr int SEQ   = 7;

__device__ __forceinline__ float sigf(float x) {
    // 1 / (1 + e^-x) with HW exp/rcp; plenty of accuracy for the 1.9e-2 threshold
    return __builtin_amdgcn_rcpf(1.0f + __expf(-x));
}

__global__ __launch_bounds__(256) void CSM_62216896250023_kernel(
    const int*   __restrict__ X,
    const float* __restrict__ emb,
    const float* __restrict__ c1,
    const float* __restrict__ c2,
    const float* __restrict__ c3,
    const float* __restrict__ c4,
    float*       __restrict__ out)
{
    const int b = blockIdx.x;
    const int e = threadIdx.x << 2;   // float4 offset within the embed dim

    __shared__ int idx[SEQ];
    if (threadIdx.x < SEQ) idx[threadIdx.x] = X[b * SEQ + threadIdx.x];
    __syncthreads();

    // Gather 7 embedding float4s
    float v[SEQ][4];
#pragma unroll
    for (int t = 0; t < SEQ; ++t) {
        const float4 f = *(const float4*)(emb + (size_t)idx[t] * EMBED + e);
        v[t][0] = f.x; v[t][1] = f.y; v[t][2] = f.z; v[t][3] = f.w;
    }

    // Conv weights for this channel group (broadcast across blocks; L1-hot)
    float k1[2][4], k2[2][4], k3[3][4], k4[3][4];
#pragma unroll
    for (int t = 0; t < 2; ++t) {
        float4 f = *(const float4*)(c1 + t * EMBED + e);
        k1[t][0] = f.x; k1[t][1] = f.y; k1[t][2] = f.z; k1[t][3] = f.w;
        f = *(const float4*)(c2 + t * EMBED + e);
        k2[t][0] = f.x; k2[t][1] = f.y; k2[t][2] = f.z; k2[t][3] = f.w;
    }
#pragma unroll
    for (int t = 0; t < 3; ++t) {
        float4 f = *(const float4*)(c3 + t * EMBED + e);
        k3[t][0] = f.x; k3[t][1] = f.y; k3[t][2] = f.z; k3[t][3] = f.w;
        f = *(const float4*)(c4 + t * EMBED + e);
        k4[t][0] = f.x; k4[t][1] = f.y; k4[t][2] = f.z; k4[t][3] = f.w;
    }

    float o[4];
#pragma unroll
    for (int j = 0; j < 4; ++j) {
        float h1[6];
#pragma unroll
        for (int l = 0; l < 6; ++l)
            h1[l] = sigf(v[l][j] * k1[0][j] + v[l + 1][j] * k1[1][j]);

        float h2[5];
#pragma unroll
        for (int l = 0; l < 5; ++l)
            h2[l] = sigf(h1[l] * k2[0][j] + h1[l + 1] * k2[1][j]);

        float h3[3];
#pragma unroll
        for (int l = 0; l < 3; ++l)
            h3[l] = sigf(h2[l] * k3[0][j] + h2[l + 1] * k3[1][j] + h2[l + 2] * k3[2][j]);

        o[j] = sigf(h3[0] * k4[0][j] + h3[1] * k4[1][j] + h3[2] * k4[2][j]);
    }

    float4 of;
    of.x = o[0]; of.y = o[1]; of.z = o[2]; of.w = o[3];
    *(float4*)(out + (size_t)b * EMBED + e) = of;
}

extern "C" void kernel_launch(void* const* d_in, const int* in_sizes, int n_in,
                              void* d_out, int out_size, void* d_ws, size_t ws_size,
                              hipStream_t stream) {
    const int*   X   = (const int*)d_in[0];
    const float* emb = (const float*)d_in[1];
    const float* c1  = (const float*)d_in[2];
    const float* c2  = (const float*)d_in[3];
    const float* c3  = (const float*)d_in[4];
    const float* c4  = (const float*)d_in[5];
    float* out = (float*)d_out;

    const int batch = in_sizes[0] / SEQ;   // 16384
    CSM_62216896250023_kernel<<<batch, 256, 0, stream>>>(X, emb, c1, c2, c3, c4, out);
}